// Round 7
// baseline (21.757 us; speedup 1.0000x reference)
//
#include <hip/hip_runtime.h>

#define B 8
#define S 2048
#define NBPS 128                        // inter blocks per sample
#define NBLK_INTER (B * NBPS)           // 1024
#define NBLK_LOSS 64                    // 64 x 256 = 16384 = B*S elems
#define NBLK_TOTAL (NBLK_INTER + NBLK_LOSS + 1)   // +1 finalizer block
#define TPB 256
#define MAGIC 0xA5C97E31u

typedef unsigned long long ull;
typedef unsigned int uint;

// ---------------------------------------------------------------------------
// Cross-block slots: one 64-bit word = {tag:32 | payload:32}. Relaxed
// agent-scope atomics only -> no fences, no L2 writebacks, no same-address
// contention. Finalizer zeroes tags after consuming (re-poison safe:
// 0xAAAAAAAA != MAGIC; stream order guarantees resets precede next replay).
// Layout in d_ws (as ull[]):
//   [0,1024)      partial  : inter per-block sums (float bits)
//   [1024,1344)   acc      : loss sums, slot ch*64+lb (float bits)
//   [1344,1352)   nbuf     : per-sample compacted counts (uint)
// ---------------------------------------------------------------------------
__device__ __forceinline__ void slot_store(ull* p, uint payload) {
    __hip_atomic_store(p, ((ull)MAGIC << 32) | (ull)payload,
                       __ATOMIC_RELAXED, __HIP_MEMORY_SCOPE_AGENT);
}
__device__ __forceinline__ uint slot_wait(ull* p) {
    ull w;
    do {
        w = __hip_atomic_load(p, __ATOMIC_RELAXED, __HIP_MEMORY_SCOPE_AGENT);
    } while ((uint)(w >> 32) != MAGIC);
    return (uint)w;
}
__device__ __forceinline__ void slot_clear(ull* p) {
    __hip_atomic_store(p, 0ull, __ATOMIC_RELAXED, __HIP_MEMORY_SCOPE_AGENT);
}

__global__ __launch_bounds__(TPB) void mega_kernel(
    const float2* __restrict__ point_pred,
    const float2* __restrict__ orient_pred,
    const float4* __restrict__ class_pred,
    const float*  __restrict__ target_seq,
    const int*    __restrict__ padding_mask,
    ull* __restrict__ slots,
    float* __restrict__ out)
{
    __shared__ float2 sp[S];                 // 16 KB
    __shared__ float red[TPB / 64][5];
    __shared__ int wsum[TPB / 64], woff[TPB / 64], nTot;

    ull* sp_partial = slots;
    ull* sp_acc     = slots + NBLK_INTER;
    ull* sp_nbuf    = slots + NBLK_INTER + 5 * NBLK_LOSS;

    const int blk = blockIdx.x;
    const int tid = threadIdx.x;
    const int lane = tid & 63, wv = tid >> 6;

    if (blk < NBLK_INTER) {
        // ================= intersection role =================
        const int b = blk >> 7;              // blk / NBPS
        const int iblk = blk & (NBPS - 1);
        const int base = b * S;
        const int e0 = tid * 8;              // 8 contiguous elems per thread

        const int4* pm4 = (const int4*)(padding_mask + base + e0);
        const int4 ma = pm4[0], mb = pm4[1];
        const float4* tr4 = (const float4*)(target_seq + (size_t)(base + e0) * 5);
        float4 tq[10];
        #pragma unroll
        for (int k = 0; k < 10; ++k) tq[k] = tr4[k];
        float t4v[8];
        t4v[0] = tq[1].x; t4v[1] = tq[2].y; t4v[2] = tq[3].z; t4v[3] = tq[4].w;
        t4v[4] = tq[6].x; t4v[5] = tq[7].y; t4v[6] = tq[8].z; t4v[7] = tq[9].w;
        const float4* pq4 = (const float4*)(point_pred + base + e0);
        const float4 pa = pq4[0], pb = pq4[1], pc = pq4[2], pd = pq4[3];
        float2 p[8];
        p[0] = make_float2(pa.x, pa.y); p[1] = make_float2(pa.z, pa.w);
        p[2] = make_float2(pb.x, pb.y); p[3] = make_float2(pb.z, pb.w);
        p[4] = make_float2(pc.x, pc.y); p[5] = make_float2(pc.z, pc.w);
        p[6] = make_float2(pd.x, pd.y); p[7] = make_float2(pd.z, pd.w);
        int f[8];
        f[0] = (ma.x == 0 && (int)t4v[0] != 0) ? 1 : 0;
        f[1] = (ma.y == 0 && (int)t4v[1] != 0) ? 1 : 0;
        f[2] = (ma.z == 0 && (int)t4v[2] != 0) ? 1 : 0;
        f[3] = (ma.w == 0 && (int)t4v[3] != 0) ? 1 : 0;
        f[4] = (mb.x == 0 && (int)t4v[4] != 0) ? 1 : 0;
        f[5] = (mb.y == 0 && (int)t4v[5] != 0) ? 1 : 0;
        f[6] = (mb.z == 0 && (int)t4v[6] != 0) ? 1 : 0;
        f[7] = (mb.w == 0 && (int)t4v[7] != 0) ? 1 : 0;

        // ---- block scan over per-thread counts (stable compaction) ----
        const int c = f[0]+f[1]+f[2]+f[3]+f[4]+f[5]+f[6]+f[7];
        int inc = c;
        #pragma unroll
        for (int off = 1; off < 64; off <<= 1) {
            int u = __shfl_up(inc, (unsigned)off, 64);
            if (lane >= off) inc += u;
        }
        if (lane == 63) wsum[wv] = inc;
        __syncthreads();
        if (tid == 0) {
            int run = 0;
            #pragma unroll
            for (int w = 0; w < TPB / 64; ++w) { woff[w] = run; run += wsum[w]; }
            nTot = run;
        }
        __syncthreads();
        int pos = woff[wv] + inc - c;        // exclusive prefix
        #pragma unroll
        for (int k = 0; k < 8; ++k) { if (f[k]) sp[pos++] = p[k]; }
        __syncthreads();

        const int n = nTot;
        if (iblk == 0 && tid == 0) slot_store(&sp_nbuf[b], (uint)n);

        // ---- pair loop ----
        float local = 0.f;
        if (n >= 4) {
            const int n_seg = n - 1;
            for (int i = iblk; i < n_seg - 2; i += NBPS) {
                const float2 q1 = sp[i], q2 = sp[i + 1];
                const float e12x = q2.x - q1.x, e12y = q2.y - q1.y;
                const int jmax = (i == 0) ? n_seg - 1 : n_seg;  // wrap-pair excl.
                for (int j = i + 2 + tid; j < jmax; j += TPB) {
                    const float2 q3 = sp[j], q4 = sp[j + 1];
                    const float e34x = q4.x - q3.x, e34y = q4.y - q3.y;
                    const float ce = e12x * e34y - e12y * e34x;
                    const float rx = q1.x - q3.x, ry = q1.y - q3.y;
                    const float d1 = e34x * ry - e34y * rx;
                    const float d3 = e12y * rx - e12x * ry;
                    const float d2 = d1 - ce;
                    const float d4 = d3 + ce;
                    const float ea = __expf(d1 * d2 * 0.01f);
                    const float eb = __expf(d3 * d4 * 0.01f);
                    // sigmoid(z1)*sigmoid(z2) = 1/((1+ea)(1+eb)); inf->rcp->0 ok
                    local += __builtin_amdgcn_rcpf((1.f + ea) * (1.f + eb));
                }
            }
        }
        #pragma unroll
        for (int off = 32; off > 0; off >>= 1)
            local += __shfl_down(local, (unsigned)off, 64);
        if (lane == 0) red[wv][0] = local;
        __syncthreads();
        if (tid == 0)
            slot_store(&sp_partial[blk],
                       __float_as_uint(red[0][0] + red[1][0] + red[2][0] + red[3][0]));
    } else if (blk < NBLK_INTER + NBLK_LOSS) {
        // ================= per-element loss role =================
        const int lb = blk - NBLK_INTER;     // [0,64)
        const int idx = lb * TPB + tid;      // [0, B*S)
        const bool valid = (padding_mask[idx] == 0);
        const float t4 = target_seq[(size_t)idx * 5 + 4];
        const int tc = (int)t4;
        const bool nn = valid && (tc != 0);
        float cls_a = 0.f, pt_a = 0.f, or_a = 0.f, v_a = 0.f, nn_a = 0.f;
        if (valid) {
            const float4 cl = class_pred[idx];
            const float m = fmaxf(fmaxf(cl.x, cl.y), fmaxf(cl.z, cl.w));
            const float lse = m + logf(expf(cl.x - m) + expf(cl.y - m) +
                                       expf(cl.z - m) + expf(cl.w - m));
            const float ct = (tc == 0) ? cl.x : (tc == 1) ? cl.y : (tc == 2) ? cl.z : cl.w;
            cls_a = lse - ct;
            v_a = 1.f;
        }
        if (nn) {
            const float2 pp = point_pred[idx];
            const float tx = target_seq[(size_t)idx * 5 + 0];
            const float ty = target_seq[(size_t)idx * 5 + 1];
            const float dx = (pp.x - tx) * (1.0f / 224.0f);
            const float dy = (pp.y - ty) * (1.0f / 224.0f);
            const float adx = fabsf(dx), ady = fabsf(dy);
            const float l0 = (adx < 1.f) ? 0.5f * dx * dx : adx - 0.5f;
            const float l1 = (ady < 1.f) ? 0.5f * dy * dy : ady - 0.5f;
            pt_a = 0.5f * (l0 + l1);
            const float2 op = orient_pred[idx];
            const float ox = target_seq[(size_t)idx * 5 + 2];
            const float oy = target_seq[(size_t)idx * 5 + 3];
            or_a = 1.f - (op.x * ox + op.y * oy);
            nn_a = 1.f;
        }
        #pragma unroll
        for (int off = 32; off > 0; off >>= 1) {
            cls_a += __shfl_down(cls_a, (unsigned)off, 64);
            pt_a  += __shfl_down(pt_a,  (unsigned)off, 64);
            or_a  += __shfl_down(or_a,  (unsigned)off, 64);
            v_a   += __shfl_down(v_a,   (unsigned)off, 64);
            nn_a  += __shfl_down(nn_a,  (unsigned)off, 64);
        }
        if (lane == 0) {
            red[wv][0] = cls_a; red[wv][1] = pt_a; red[wv][2] = or_a;
            red[wv][3] = v_a;   red[wv][4] = nn_a;
        }
        __syncthreads();
        if (tid == 0) {
            #pragma unroll
            for (int c5 = 0; c5 < 5; ++c5)
                slot_store(&sp_acc[c5 * NBLK_LOSS + lb],
                           __float_as_uint(red[0][c5] + red[1][c5] +
                                           red[2][c5] + red[3][c5]));
        }
    } else {
        // ================= finalizer role (1 block) =================
        // spin-collect intersection partials: 4 slots/thread
        float s = 0.f;
        #pragma unroll
        for (int k = 0; k < 4; ++k)
            s += __uint_as_float(slot_wait(&sp_partial[tid + TPB * k]));
        #pragma unroll
        for (int off = 32; off > 0; off >>= 1)
            s += __shfl_down(s, (unsigned)off, 64);
        if (lane == 0) red[wv][0] = s;
        __syncthreads();
        const float inter_sum = red[0][0] + red[1][0] + red[2][0] + red[3][0];

        // loss channels: wave 0, one lane per loss-block
        float a[5] = {0.f, 0.f, 0.f, 0.f, 0.f};
        if (wv == 0) {
            #pragma unroll
            for (int ch = 0; ch < 5; ++ch)
                a[ch] = __uint_as_float(slot_wait(&sp_acc[ch * NBLK_LOSS + lane]));
            #pragma unroll
            for (int off = 32; off > 0; off >>= 1) {
                #pragma unroll
                for (int ch = 0; ch < 5; ++ch)
                    a[ch] += __shfl_down(a[ch], (unsigned)off, 64);
            }
        }

        if (tid == 0) {
            long long cnt = 0;
            #pragma unroll
            for (int b2 = 0; b2 < B; ++b2) {
                const int n = (int)slot_wait(&sp_nbuf[b2]);
                if (n >= 4) {
                    const long long ns = n - 1;
                    cnt += (ns - 1) * (ns - 2) / 2 - 1;
                }
            }
            const float cls_loss = a[0] / fmaxf(a[3], 1.f);
            const float pt_loss = a[1] / fmaxf(a[4], 1.f);
            const float orient_loss = a[2] / fmaxf(a[4], 1.f);
            const float intersect_loss = (cnt > 0) ? inter_sum / (float)cnt : 0.f;
            out[0] = 1.0f * pt_loss + 0.5f * orient_loss +
                     1.0f * cls_loss + 0.1f * intersect_loss;
            out[1] = pt_loss;
            out[2] = orient_loss;
            out[3] = cls_loss;
            out[4] = intersect_loss;
        }

        // reset tags for the next replay (stream order makes this safe)
        #pragma unroll
        for (int k = 0; k < 4; ++k) slot_clear(&sp_partial[tid + TPB * k]);
        if (wv == 0) {
            #pragma unroll
            for (int ch = 0; ch < 5; ++ch) slot_clear(&sp_acc[ch * NBLK_LOSS + lane]);
        }
        if (tid == 0) {
            #pragma unroll
            for (int b2 = 0; b2 < B; ++b2) slot_clear(&sp_nbuf[b2]);
        }
    }
}

extern "C" void kernel_launch(void* const* d_in, const int* in_sizes, int n_in,
                              void* d_out, int out_size, void* d_ws, size_t ws_size,
                              hipStream_t stream) {
    (void)in_sizes; (void)n_in; (void)out_size; (void)ws_size;
    const float2* point_pred  = (const float2*)d_in[0];
    const float2* orient_pred = (const float2*)d_in[1];
    const float4* class_pred  = (const float4*)d_in[2];
    const float*  target_seq  = (const float*)d_in[3];
    const int*    padding_mask = (const int*)d_in[4];

    mega_kernel<<<NBLK_TOTAL, TPB, 0, stream>>>(point_pred, orient_pred,
                                                class_pred, target_seq,
                                                padding_mask,
                                                (ull*)d_ws, (float*)d_out);
}